// Round 1
// baseline (557.578 us; speedup 1.0000x reference)
//
#include <hip/hip_runtime.h>

typedef unsigned short u16;
typedef unsigned int u32;
typedef __bf16 bf16x8 __attribute__((ext_vector_type(8)));
typedef float f32x4 __attribute__((ext_vector_type(4)));

#define B_ 2
#define S_ 2048
#define D_ 2048
#define H_ 16
#define HD_ 128

__device__ __forceinline__ u16 f2bf(float f) {
  u32 u = __float_as_uint(f);
  u32 r = (u + 0x7fffu + ((u >> 16) & 1u)) >> 16;
  return (u16)r;
}
__device__ __forceinline__ float bf2f(u16 b) {
  return __uint_as_float(((u32)b) << 16);
}

// async global->LDS, 16B per lane. LDS dest must be linear in lane order.
__device__ __forceinline__ void gll16(const void* g, void* lds) {
  __builtin_amdgcn_global_load_lds(
      (const __attribute__((address_space(1))) u32*)g,
      (__attribute__((address_space(3))) u32*)lds, 16, 0, 0);
}

// ---------------- f32 -> bf16 cast ----------------
__global__ __launch_bounds__(256) void cvt_bf16(const float* __restrict__ in,
                                                u16* __restrict__ out, int n4) {
  int i = blockIdx.x * 256 + threadIdx.x;
  if (i >= n4) return;
  float4 v = ((const float4*)in)[i];
  u16 o[4] __attribute__((aligned(8)));
  o[0] = f2bf(v.x); o[1] = f2bf(v.y); o[2] = f2bf(v.z); o[3] = f2bf(v.w);
  ((ushort4*)out)[i] = *(const ushort4*)o;
}

// ---------------- RoPE (in-place on (B,H,S,HD) bf16), optional scale ----------------
__global__ __launch_bounds__(256) void rope_k(u16* __restrict__ x,
                                              const float* __restrict__ cosb,
                                              const float* __restrict__ sinb,
                                              float scale) {
  int tid = blockIdx.x * 256 + threadIdx.x;  // 8 elems per thread
  int flat = tid << 3;
  int hd0 = flat & (HD_ - 1);
  int s = (flat >> 7) & (S_ - 1);
  u16 e[8] __attribute__((aligned(16)));
  *(uint4*)e = *(const uint4*)&x[flat];
  const float* cp = cosb + s * (HD_ / 2) + (hd0 >> 1);
  const float* sp = sinb + s * (HD_ / 2) + (hd0 >> 1);
#pragma unroll
  for (int i = 0; i < 4; ++i) {
    float xr = bf2f(e[2 * i]), xi = bf2f(e[2 * i + 1]);
    float c = cp[i], sn = sp[i];
    e[2 * i]     = f2bf((xr * c - xi * sn) * scale);
    e[2 * i + 1] = f2bf((xr * sn + xi * c) * scale);
  }
  *(uint4*)&x[flat] = *(const uint4*)e;
}

// ---------------- V transpose: (B,H,S,HD) -> (B,H,HD,S) ----------------
__global__ __launch_bounds__(256) void transpose_v(const u16* __restrict__ v,
                                                   u16* __restrict__ vt) {
  __shared__ u16 tile[64][72];
  int s0 = blockIdx.x * 64, hd0 = blockIdx.y * 64, bh = blockIdx.z;
  const u16* vh = v + (size_t)bh * S_ * HD_;
  u16* vth = vt + (size_t)bh * S_ * HD_;
  int t = threadIdx.x;
#pragma unroll
  for (int it = 0; it < 2; ++it) {
    int f = it * 256 + t;
    int r = f >> 3, c = (f & 7) * 8;
    *(uint4*)&tile[r][c] = *(const uint4*)&vh[(size_t)(s0 + r) * HD_ + hd0 + c];
  }
  __syncthreads();
#pragma unroll
  for (int it = 0; it < 2; ++it) {
    int f = it * 256 + t;
    int r = f >> 3, c = (f & 7) * 8;   // r: hd row of vt, c: s col chunk
    u16 tmp[8] __attribute__((aligned(16)));
#pragma unroll
    for (int j = 0; j < 8; ++j) tmp[j] = tile[c + j][r];
    *(uint4*)&vth[(size_t)(hd0 + r) * S_ + s0 + c] = *(const uint4*)tmp;
  }
}

// ---------------- GEMM C[m,n] = sum_k A[m,k]*W[n,k]  (M=4096,N=2048,K=2048) ----------------
// m97 structure: 128x128 tile, BK=64, 4 waves (2x2), global_load_lds width=16.
// outf32==0: writes bf16 to Db permuted (B,H,S,HD). outf32==1: writes f32 to DF (B,S,D).
__global__ __launch_bounds__(256) void gemm_bt(
    const u16* __restrict__ A,
    const u16* __restrict__ Wq, const u16* __restrict__ Wk, const u16* __restrict__ Wv,
    u16* __restrict__ Dq, u16* __restrict__ Dk, u16* __restrict__ Dv,
    float* __restrict__ DF, int outf32) {
  const u16* W = (blockIdx.z == 0) ? Wq : (blockIdx.z == 1) ? Wk : Wv;
  u16* Db = (blockIdx.z == 0) ? Dq : (blockIdx.z == 1) ? Dk : Dv;
  __shared__ u16 At[128 * 64] __attribute__((aligned(16)));
  __shared__ u16 Bt[128 * 64] __attribute__((aligned(16)));
  const int t = threadIdx.x, l = t & 63;
  const int w = t >> 6, wr = w >> 1, wc = w & 1;
  const int m0 = blockIdx.y * 128, n0 = blockIdx.x * 128;
  f32x4 acc[4][4];
#pragma unroll
  for (int i = 0; i < 4; ++i)
#pragma unroll
    for (int j = 0; j < 4; ++j) acc[i][j] = (f32x4){0.f, 0.f, 0.f, 0.f};
  const int row_s = t >> 3;
  const int col_s = (t & 7) * 8;
  for (int kt = 0; kt < 2048; kt += 64) {
    __syncthreads();
#pragma unroll
    for (int it = 0; it < 4; ++it) {
      int f = it * 256 + t;
      int row = it * 32 + row_s;
      gll16(&A[(size_t)(m0 + row) * 2048 + kt + col_s], &At[f * 8]);
      gll16(&W[(size_t)(n0 + row) * 2048 + kt + col_s], &Bt[f * 8]);
    }
    __syncthreads();
#pragma unroll
    for (int kk = 0; kk < 2; ++kk) {
      const int ko = kk * 32 + (l >> 4) * 8;
      bf16x8 av[4], bv[4];
#pragma unroll
      for (int i = 0; i < 4; ++i)
        av[i] = *(const bf16x8*)&At[(wr * 64 + i * 16 + (l & 15)) * 64 + ko];
#pragma unroll
      for (int i = 0; i < 4; ++i)
        bv[i] = *(const bf16x8*)&Bt[(wc * 64 + i * 16 + (l & 15)) * 64 + ko];
#pragma unroll
      for (int i = 0; i < 4; ++i)
#pragma unroll
        for (int j = 0; j < 4; ++j)
          acc[i][j] = __builtin_amdgcn_mfma_f32_16x16x32_bf16(av[i], bv[j], acc[i][j], 0, 0, 0);
    }
  }
#pragma unroll
  for (int i = 0; i < 4; ++i) {
#pragma unroll
    for (int j = 0; j < 4; ++j) {
#pragma unroll
      for (int r = 0; r < 4; ++r) {
        int m = m0 + wr * 64 + i * 16 + (l >> 4) * 4 + r;
        int n = n0 + wc * 64 + j * 16 + (l & 15);
        float val = acc[i][j][r];
        if (outf32) {
          DF[(size_t)m * 2048 + n] = val;
        } else {
          int b = m >> 11, s = m & 2047, h = n >> 7, hd = n & 127;
          Db[(((size_t)(b * 16 + h)) * 2048 + s) * 128 + hd] = f2bf(val);
        }
      }
    }
  }
}

// ---------------- Flash attention: q,k (B,H,S,HD), vt (B,H,HD,S), o (B,S,D) bf16 ----------------
// q pre-scaled by (1/sqrt(HD))*log2(e) so softmax uses exp2.
__global__ __launch_bounds__(256) void attn_fwd(
    const u16* __restrict__ q, const u16* __restrict__ k, const u16* __restrict__ vt,
    u16* __restrict__ o) {
  const int qt = blockIdx.x, bh = blockIdx.y;
  const u16* qh = q + (size_t)bh * S_ * HD_;
  const u16* kh = k + (size_t)bh * S_ * HD_;
  const u16* vth = vt + (size_t)bh * S_ * HD_;
  const int q0 = qt * 64;
  const int t = threadIdx.x, l = t & 63, w = t >> 6;
  __shared__ u16 Kl[64][136] __attribute__((aligned(16)));   // +8 pad: 2-way banks
  __shared__ u16 Vl[128][72] __attribute__((aligned(16)));   // [hd][kv], +8 pad
  __shared__ u16 Pl[4][16][72] __attribute__((aligned(16))); // per-wave P
  const int qrow = q0 + w * 16 + (l & 15);
  bf16x8 qf[4];
#pragma unroll
  for (int kk = 0; kk < 4; ++kk)
    qf[kk] = *(const bf16x8*)&qh[(size_t)qrow * HD_ + kk * 32 + (l >> 4) * 8];
  f32x4 oacc[8];
#pragma unroll
  for (int i = 0; i < 8; ++i) oacc[i] = (f32x4){0.f, 0.f, 0.f, 0.f};
  float mrow[4] = {-1e30f, -1e30f, -1e30f, -1e30f};
  float lrow[4] = {0.f, 0.f, 0.f, 0.f};
  const int ntile = qt + 1;  // causal: kv tiles 0..qt
  for (int tk = 0; tk < ntile; ++tk) {
    const int kv0 = tk * 64;
    __syncthreads();
#pragma unroll
    for (int it = 0; it < 4; ++it) {           // stage K tile [64][128]
      int f = it * 256 + t;
      int r = f >> 4, c = (f & 15) * 8;
      *(uint4*)&Kl[r][c] = *(const uint4*)&kh[(size_t)(kv0 + r) * HD_ + c];
    }
#pragma unroll
    for (int it = 0; it < 4; ++it) {           // stage Vt tile [128][64]
      int f = it * 256 + t;
      int r = f >> 3, c = (f & 7) * 8;
      *(uint4*)&Vl[r][c] = *(const uint4*)&vth[(size_t)r * S_ + kv0 + c];
    }
    __syncthreads();
    f32x4 sf[4];
#pragma unroll
    for (int cb = 0; cb < 4; ++cb) sf[cb] = (f32x4){0.f, 0.f, 0.f, 0.f};
#pragma unroll
    for (int kk = 0; kk < 4; ++kk) {
      const int ko = kk * 32 + (l >> 4) * 8;
#pragma unroll
      for (int cb = 0; cb < 4; ++cb) {
        bf16x8 bfr = *(const bf16x8*)&Kl[cb * 16 + (l & 15)][ko];
        sf[cb] = __builtin_amdgcn_mfma_f32_16x16x32_bf16(qf[kk], bfr, sf[cb], 0, 0, 0);
      }
    }
    if (tk == qt) {  // causal mask on diagonal tile
      const int rbase = w * 16 + (l >> 4) * 4;
#pragma unroll
      for (int cb = 0; cb < 4; ++cb) {
        int c = cb * 16 + (l & 15);
#pragma unroll
        for (int r = 0; r < 4; ++r)
          if (c > rbase + r) sf[cb][r] = -1e30f;
      }
    }
    float fr[4], ps[4];
#pragma unroll
    for (int r = 0; r < 4; ++r) {
      float v0 = fmaxf(fmaxf(sf[0][r], sf[1][r]), fmaxf(sf[2][r], sf[3][r]));
      v0 = fmaxf(v0, __shfl_xor(v0, 1));
      v0 = fmaxf(v0, __shfl_xor(v0, 2));
      v0 = fmaxf(v0, __shfl_xor(v0, 4));
      v0 = fmaxf(v0, __shfl_xor(v0, 8));
      float Mn = fmaxf(mrow[r], v0);
      fr[r] = exp2f(mrow[r] - Mn);
      mrow[r] = Mn;
      ps[r] = 0.f;
    }
#pragma unroll
    for (int cb = 0; cb < 4; ++cb) {
#pragma unroll
      for (int r = 0; r < 4; ++r) {
        float p = exp2f(sf[cb][r] - mrow[r]);
        ps[r] += p;
        Pl[w][(l >> 4) * 4 + r][cb * 16 + (l & 15)] = f2bf(p);
      }
    }
#pragma unroll
    for (int r = 0; r < 4; ++r) {
      float s = ps[r];
      s += __shfl_xor(s, 1);
      s += __shfl_xor(s, 2);
      s += __shfl_xor(s, 4);
      s += __shfl_xor(s, 8);
      lrow[r] = lrow[r] * fr[r] + s;
    }
#pragma unroll
    for (int i = 0; i < 8; ++i)
#pragma unroll
      for (int r = 0; r < 4; ++r) oacc[i][r] *= fr[r];
#pragma unroll
    for (int ks = 0; ks < 2; ++ks) {
      bf16x8 pa = *(const bf16x8*)&Pl[w][l & 15][ks * 32 + (l >> 4) * 8];
#pragma unroll
      for (int nf = 0; nf < 8; ++nf) {
        bf16x8 vb = *(const bf16x8*)&Vl[nf * 16 + (l & 15)][ks * 32 + (l >> 4) * 8];
        oacc[nf] = __builtin_amdgcn_mfma_f32_16x16x32_bf16(pa, vb, oacc[nf], 0, 0, 0);
      }
    }
  }
  const int b = bh >> 4, h = bh & 15;
  float inv[4];
#pragma unroll
  for (int r = 0; r < 4; ++r) inv[r] = 1.f / lrow[r];
#pragma unroll
  for (int nf = 0; nf < 8; ++nf) {
#pragma unroll
    for (int r = 0; r < 4; ++r) {
      int row = q0 + w * 16 + (l >> 4) * 4 + r;
      int col = h * 128 + nf * 16 + (l & 15);
      o[((size_t)(b * 2048 + row)) * 2048 + col] = f2bf(oacc[nf][r] * inv[r]);
    }
  }
}

extern "C" void kernel_launch(void* const* d_in, const int* in_sizes, int n_in,
                              void* d_out, int out_size, void* d_ws, size_t ws_size,
                              hipStream_t stream) {
  (void)in_sizes; (void)n_in; (void)out_size; (void)ws_size;
  const float* hs   = (const float*)d_in[0];
  const float* fcos = (const float*)d_in[1];
  const float* fsin = (const float*)d_in[2];
  // d_in[3] = attention_mask: causal, implemented directly.
  const float* wq = (const float*)d_in[4];
  const float* wk = (const float*)d_in[5];
  const float* wv = (const float*)d_in[6];
  const float* wo = (const float*)d_in[7];
  float* out = (float*)d_out;
  char* ws = (char*)d_ws;
  // ws layout (bytes), total 128 MiB
  u16* hsb = (u16*)(ws + 0);          // 16 MiB  hs bf16 (B,S,D)
  u16* wqb = (u16*)(ws + 16777216);
  u16* wkb = (u16*)(ws + 25165824);
  u16* wvb = (u16*)(ws + 33554432);
  u16* wob = (u16*)(ws + 41943040);
  u16* qb  = (u16*)(ws + 50331648);   // (B,H,S,HD) bf16
  u16* kb  = (u16*)(ws + 67108864);
  u16* vb  = (u16*)(ws + 83886080);
  u16* vtb = (u16*)(ws + 100663296);  // (B,H,HD,S) bf16
  u16* aob = (u16*)(ws + 117440512);  // (B,S,D) bf16 attention output

  cvt_bf16<<<8192, 256, 0, stream>>>(hs, hsb, 2097152);
  cvt_bf16<<<4096, 256, 0, stream>>>(wq, wqb, 1048576);
  cvt_bf16<<<4096, 256, 0, stream>>>(wk, wkb, 1048576);
  cvt_bf16<<<4096, 256, 0, stream>>>(wv, wvb, 1048576);
  cvt_bf16<<<4096, 256, 0, stream>>>(wo, wob, 1048576);

  gemm_bt<<<dim3(16, 32, 3), 256, 0, stream>>>(hsb, wqb, wkb, wvb, qb, kb, vb, nullptr, 0);

  const float qscale = (float)(0.08838834764831845 * 1.4426950408889634); // 1/sqrt(128)*log2(e)
  rope_k<<<4096, 256, 0, stream>>>(qb, fcos, fsin, qscale);
  rope_k<<<4096, 256, 0, stream>>>(kb, fcos, fsin, 1.0f);

  transpose_v<<<dim3(32, 2, 32), 256, 0, stream>>>(vb, vtb);

  attn_fwd<<<dim3(32, 32), 256, 0, stream>>>(qb, kb, vtb, aob);

  gemm_bt<<<dim3(16, 32, 1), 256, 0, stream>>>(aob, wob, wob, wob,
                                               nullptr, nullptr, nullptr, out, 1);
}